// Round 3
// baseline (1428.664 us; speedup 1.0000x reference)
//
#include <hip/hip_runtime.h>
#include <hip/hip_bf16.h>
#include <math.h>

typedef __hip_bfloat16 bf16;
using short8 = __attribute__((ext_vector_type(8))) short;
using f32x4  = __attribute__((ext_vector_type(4))) float;

#define NB 8
#define NC 256
#define NH 128
#define NW 128
#define NHW 16384
#define MID 128

__device__ __forceinline__ float b2f(bf16 v){ return __bfloat162float(v); }
__device__ __forceinline__ bf16 f2b(float v){ return __float2bfloat16(v); }
#define BN_S 0.9999950000374997f  /* 1/sqrt(1+1e-5) */

// ---------------- f32 -> bf16 weight convert ----------------
__global__ __launch_bounds__(256) void k_cvt(const float* __restrict__ src, bf16* __restrict__ dst, int n){
  int i = blockIdx.x*256 + threadIdx.x;
  if(i < n) dst[i] = f2b(src[i]);
}

// ---------------- hm_c3 (m,c,3,3) f32 -> (tau,m,c) bf16 ----------------
__global__ __launch_bounds__(256) void k_trans(const float* __restrict__ src, bf16* __restrict__ dst){
  int i = blockIdx.x*256 + threadIdx.x;
  if(i >= MID*MID*9) return;
  int tau = i % 9; int c = (i/9) % MID; int m = i/(9*MID);
  dst[((size_t)tau*MID + m)*MID + c] = f2b(src[i]);
}

// ============ fused: depthwise3x3(f32) -> bf16 -> pointwise MFMA GEMM -> bn/relu -> epilogue ============
// MODE 0: store all M channels as bf16 (h1)
// MODE 1: radius head: rmap = RMIN + sigmoid(dot(hw, relu(bn(.))) + hb)*(RMAX-RMIN)  (f32 out)
// block 256 = 4 waves; tile = 64 consecutive pixels (one row segment) x M (=MT*16)
template<int MT, int MODE>
__global__ __launch_bounds__(256) void k_pw_fused(const float* __restrict__ x,
                                                  const float* __restrict__ dw,   // (C,9)
                                                  const bf16*  __restrict__ wA,   // (M,C) bf16
                                                  const float* __restrict__ g,
                                                  const float* __restrict__ bias,
                                                  const float* __restrict__ hw,   // head w (MODE1)
                                                  const float* __restrict__ hb,   // head b (MODE1)
                                                  bf16*  __restrict__ outCh,      // (B,M,NHW) MODE0
                                                  float* __restrict__ outMap){    // (B,NHW) MODE1
  __shared__ ushort ldsB[64][32];   // [pixel][k]
  const int M = MT*16;
  int tid = threadIdx.x;
  int bidx = blockIdx.x;
  int b = bidx >> 8;
  int p0 = (bidx & 255)*64;
  int lane = tid & 63, wave = tid >> 6;
  int px = tid & 63, cg = tid >> 6;
  int p = p0 + px;
  int y = p >> 7, xx = p & 127;
  const float*  xB = x + (size_t)b*NC*NHW;
  const ushort* wU = (const ushort*)wA;

  f32x4 acc[MT];
  #pragma unroll
  for(int i=0;i<MT;i++){
    #pragma unroll
    for(int r=0;r<4;r++) acc[i][r] = 0.f;
  }

  for(int k0=0;k0<NC;k0+=32){
    __syncthreads();
    union { ushort u[8]; uint4 v; } t;
    #pragma unroll
    for(int j=0;j<8;j++){
      int ch = k0 + cg*8 + j;
      const float* xc = xB + (size_t)ch*NHW;
      const float* wc = dw + ch*9;
      float a = 0.f;
      #pragma unroll
      for(int dy=-1;dy<=1;dy++){
        int yy = y+dy;
        if(yy<0||yy>=NH) continue;
        #pragma unroll
        for(int dx=-1;dx<=1;dx++){
          int xc2 = xx+dx;
          if(xc2<0||xc2>=NW) continue;
          a += xc[yy*NW + xc2] * wc[(dy+1)*3+(dx+1)];
        }
      }
      bf16 ab = f2b(a);
      t.u[j] = *(ushort*)&ab;
    }
    *(uint4*)&ldsB[px][cg*8] = t.v;
    __syncthreads();
    short8 bfrag = *(const short8*)&ldsB[wave*16 + (lane&15)][(lane>>4)*8];
    #pragma unroll
    for(int mt=0;mt<MT;mt++){
      short8 afrag = *(const short8*)&wU[(size_t)(mt*16 + (lane&15))*NC + k0 + (lane>>4)*8];
      acc[mt] = __builtin_amdgcn_mfma_f32_16x16x32_bf16(afrag, bfrag, acc[mt], 0, 0, 0);
    }
  }

  int pix = p0 + wave*16 + (lane&15);
  if(MODE == 0){
    #pragma unroll
    for(int mt=0;mt<MT;mt++){
      #pragma unroll
      for(int r=0;r<4;r++){
        int m = mt*16 + (lane>>4)*4 + r;
        float v = acc[mt][r]*(g[m]*BN_S) + bias[m];
        outCh[((size_t)(b*M + m))*NHW + pix] = f2b(fmaxf(v, 0.f));
      }
    }
  }else{
    float ph = 0.f;
    #pragma unroll
    for(int mt=0;mt<MT;mt++){
      #pragma unroll
      for(int r=0;r<4;r++){
        int m = mt*16 + (lane>>4)*4 + r;
        float v = acc[mt][r]*(g[m]*BN_S) + bias[m];
        ph += fmaxf(v, 0.f) * hw[m];
      }
    }
    ph += __shfl_xor(ph, 16);
    ph += __shfl_xor(ph, 32);
    if(lane < 16){
      float sg = 1.f/(1.f + expf(-(ph + hb[0])));
      outMap[(size_t)b*NHW + pix] = 0.03f + sg*0.37f;  // RMIN + sg*(RMAX-RMIN)
    }
  }
}

// ============ 3x3 conv MID->MID (9 shifted GEMMs) + bn/relu + heat head + sigmoid ============
__global__ __launch_bounds__(256) void k_c3(const bf16* __restrict__ in,   // h1 (B,MID,NHW) bf16
                                            const bf16* __restrict__ wT,   // (tau,m,c) bf16
                                            const float* __restrict__ g,
                                            const float* __restrict__ bias,
                                            const float* __restrict__ hw,  // hm_out_w (MID)
                                            const float* __restrict__ hb,  // hm_out_b (1)
                                            float* __restrict__ heatF,     // (B,NHW)
                                            float* __restrict__ out){      // (B,2,NHW) -> ch1
  __shared__ ushort ldsB[64][32];
  int tid = threadIdx.x;
  int bidx = blockIdx.x;
  int b = bidx >> 8;
  int p0 = (bidx & 255)*64;
  int y = p0 >> 7;
  int x0 = p0 & 127;
  const ushort* inU = (const ushort*)(in + (size_t)b*MID*NHW);
  const ushort* wU  = (const ushort*)wT;
  int lane = tid & 63, wave = tid >> 6;
  int px = tid & 63, cg = tid >> 6;
  f32x4 acc[8];
  #pragma unroll
  for(int i=0;i<8;i++){
    #pragma unroll
    for(int r=0;r<4;r++) acc[i][r] = 0.f;
  }
  for(int tau=0;tau<9;tau++){
    int dy = tau/3 - 1, dx = tau%3 - 1;
    int yy = y + dy;
    int xs = x0 + px + dx;
    bool ok = (yy>=0) && (yy<NH) && (xs>=0) && (xs<NW);
    long sbase = (long)yy*NW + xs;
    const ushort* wtb = wU + (size_t)tau*MID*MID;
    for(int k0=0;k0<MID;k0+=32){
      __syncthreads();
      union { ushort u[8]; uint4 v; } t;
      #pragma unroll
      for(int j=0;j<8;j++){
        long idx = (long)(k0 + cg*8 + j)*NHW + sbase;
        t.u[j] = ok ? inU[idx] : (ushort)0;
      }
      *(uint4*)&ldsB[px][cg*8] = t.v;
      __syncthreads();
      short8 bfrag = *(const short8*)&ldsB[wave*16 + (lane&15)][(lane>>4)*8];
      #pragma unroll
      for(int mt=0;mt<8;mt++){
        short8 afrag = *(const short8*)&wtb[(size_t)(mt*16 + (lane&15))*MID + k0 + (lane>>4)*8];
        acc[mt] = __builtin_amdgcn_mfma_f32_16x16x32_bf16(afrag, bfrag, acc[mt], 0, 0, 0);
      }
    }
  }
  float ph = 0.f;
  #pragma unroll
  for(int mt=0;mt<8;mt++){
    #pragma unroll
    for(int r=0;r<4;r++){
      int m = mt*16 + (lane>>4)*4 + r;
      float v = acc[mt][r]*(g[m]*BN_S) + bias[m];
      ph += fmaxf(v, 0.f) * hw[m];
    }
  }
  ph += __shfl_xor(ph, 16);
  ph += __shfl_xor(ph, 32);
  if(lane < 16){
    int pix = p0 + wave*16 + lane;
    float sg = 1.f/(1.f + expf(-(ph + hb[0])));
    heatF[(size_t)b*NHW + pix] = sg;
    out[((size_t)(b*2+1))*NHW + pix] = sg;
  }
}

// ---------------- peaks (3x3 maxpool mask) + top-5 + centers ----------------
__global__ __launch_bounds__(256) void k_topk(const float* __restrict__ heat,
                                              float* __restrict__ centers){
  __shared__ float sv[256*5];
  __shared__ int   si[256*5];
  int b = blockIdx.x, tid = threadIdx.x;
  const float* hb = heat + (size_t)b*NHW;
  float tv[5]; int ti[5];
  #pragma unroll
  for(int i=0;i<5;i++){ tv[i] = -1.f; ti[i] = 0x7fffffff; }
  for(int p = tid; p < NHW; p += 256){
    int y = p >> 7, x = p & 127;
    float v = hb[p];
    float mx = v;
    for(int dy=-1;dy<=1;dy++){
      int yy = y+dy; if(yy<0||yy>=NH) continue;
      for(int dx=-1;dx<=1;dx++){
        int xc = x+dx; if(xc<0||xc>=NW) continue;
        mx = fmaxf(mx, hb[yy*NW+xc]);
      }
    }
    float pv = (v == mx) ? v : 0.f;
    #pragma unroll
    for(int j=0;j<5;j++){
      if(pv > tv[j] || (pv == tv[j] && p < ti[j])){
        for(int q=4;q>j;q--){ tv[q]=tv[q-1]; ti[q]=ti[q-1]; }
        tv[j] = pv; ti[j] = p;
        break;
      }
    }
  }
  #pragma unroll
  for(int i=0;i<5;i++){ sv[tid*5+i] = tv[i]; si[tid*5+i] = ti[i]; }
  __syncthreads();
  if(tid < 64){
    float mv[5]; int mi[5];
    #pragma unroll
    for(int i=0;i<5;i++){ mv[i] = -1.f; mi[i] = 0x7fffffff; }
    for(int s=0;s<4;s++){
      int t2 = tid + s*64;
      for(int i=0;i<5;i++){
        float pv = sv[t2*5+i]; int pi = si[t2*5+i];
        for(int j=0;j<5;j++){
          if(pv > mv[j] || (pv == mv[j] && pi < mi[j])){
            for(int q=4;q>j;q--){ mv[q]=mv[q-1]; mi[q]=mi[q-1]; }
            mv[j] = pv; mi[j] = pi;
            break;
          }
        }
      }
    }
    for(int i=0;i<5;i++){ sv[tid*5+i] = mv[i]; si[tid*5+i] = mi[i]; }
  }
  __syncthreads();
  if(tid == 0){
    float fv[5]; int fi[5];
    #pragma unroll
    for(int i=0;i<5;i++){ fv[i] = -1.f; fi[i] = 0x7fffffff; }
    for(int t2=0;t2<64;t2++){
      for(int i=0;i<5;i++){
        float pv = sv[t2*5+i]; int pi = si[t2*5+i];
        for(int j=0;j<5;j++){
          if(pv > fv[j] || (pv == fv[j] && pi < fi[j])){
            for(int q=4;q>j;q--){ fv[q]=fv[q-1]; fi[q]=fi[q-1]; }
            fv[j] = pv; fi[j] = pi;
            break;
          }
        }
      }
    }
    for(int k=0;k<5;k++){
      float val = fv[k]; int idx = fi[k];
      float valid = (val >= 0.1f) ? 1.f : 0.f;
      float row = (float)(idx >> 7);
      float col = (float)(idx & 127);
      float ny = 2.f*row/127.f - 1.f;
      float nx = 2.f*col/127.f - 1.f;
      float* cp = centers + (b*5+k)*4;
      cp[0] = nx*valid; cp[1] = ny*valid; cp[2] = val; cp[3] = valid;
    }
  }
}

// ---------------- bilinear sample + MLP -> per-(b,k) gaussian params (all f32) ----------------
__global__ __launch_bounds__(256) void k_params(const float* __restrict__ x,
                                                const float* __restrict__ rmap,
                                                const float* __restrict__ centers,
                                                const float* __restrict__ w1,
                                                const float* __restrict__ b1,
                                                const float* __restrict__ w2,
                                                const float* __restrict__ b2,
                                                const float* __restrict__ log_alpha,
                                                float* __restrict__ params){
  __shared__ float feat[NC];
  __shared__ float hmid[128];
  __shared__ float pp[4];
  int b = blockIdx.x, tid = threadIdx.x;
  for(int k=0;k<5;k++){
    float cx = centers[(b*5+k)*4+0];
    float cy = centers[(b*5+k)*4+1];
    float valid = centers[(b*5+k)*4+3];
    float px = fminf(fmaxf((cx+1.f)*0.5f*(NW-1), 0.f), (float)(NW-1));
    float py = fminf(fmaxf((cy+1.f)*0.5f*(NH-1), 0.f), (float)(NH-1));
    int x0 = (int)floorf(px); int x1 = min(x0+1, NW-1);
    int y0 = (int)floorf(py); int y1 = min(y0+1, NH-1);
    float wx = px - (float)x0, wy = py - (float)y0;
    {
      const float* xb = x + ((size_t)b*NC + tid)*NHW;
      float v00 = xb[y0*NW+x0], v01 = xb[y0*NW+x1];
      float v10 = xb[y1*NW+x0], v11 = xb[y1*NW+x1];
      feat[tid] = (1.f-wy)*((1.f-wx)*v00 + wx*v01) + wy*((1.f-wx)*v10 + wx*v11);
    }
    __syncthreads();
    if(tid < 128){
      float a = b1[tid];
      for(int c=0;c<NC;c++) a += feat[c]*w1[c*128+tid];
      hmid[tid] = fmaxf(a, 0.f);
    }
    __syncthreads();
    if(tid < 4){
      float a = b2[tid];
      for(int j=0;j<128;j++) a += hmid[j]*w2[j*4+tid];
      pp[tid] = a;
    }
    __syncthreads();
    if(tid == 0){
      const float* rb = rmap + (size_t)b*NHW;
      float r00 = rb[y0*NW+x0], r01 = rb[y0*NW+x1];
      float r10 = rb[y1*NW+x0], r11 = rb[y1*NW+x1];
      float rk = (1.f-wy)*((1.f-wx)*r00 + wx*r01) + wy*((1.f-wx)*r10 + wx*r11);
      float la = log_alpha[0];
      float alpha = logf(1.f + expf(la));
      float dsx = tanhf(pp[0])*0.08f;
      float dsy = tanhf(pp[1])*0.08f;
      float theta = tanhf(pp[2])*3.14159265358979323846f;
      float wgt = 1.f/(1.f + expf(-pp[3]));
      float sx = fminf(fmaxf(alpha*rk + dsx, 0.05f), 0.45f);
      float sy = fminf(fmaxf(alpha*rk*1.5f + dsy, 0.05f), 0.45f);
      float* P = params + (b*5+k)*8;
      P[0] = cx; P[1] = cy;
      P[2] = cosf(theta); P[3] = sinf(theta);
      P[4] = 1.f/(2.f*sx*sx + 1e-6f);
      P[5] = 1.f/(2.f*sy*sy + 1e-6f);
      P[6] = wgt*valid; P[7] = valid;
    }
    __syncthreads();
  }
}

// ---------------- gaussian mixture -> attn (out ch0) ----------------
__global__ __launch_bounds__(256) void k_attn(const float* __restrict__ params,
                                              float* __restrict__ out){
  int tid = threadIdx.x;
  int p = blockIdx.x*256 + tid;
  int b = blockIdx.y;
  int y = p >> 7, x = p & 127;
  float gx = -1.f + 2.f*(float)x/127.f;
  float gy = -1.f + 2.f*(float)y/127.f;
  const float* Pb = params + b*40;
  float wsum = 0.f;
  #pragma unroll
  for(int k=0;k<5;k++) wsum += Pb[k*8+6];
  wsum = fmaxf(wsum, 1e-6f);
  float mix = 0.f;
  #pragma unroll
  for(int k=0;k<5;k++){
    const float* P = Pb + k*8;
    float dx = gx - P[0], dy = gy - P[1];
    float xr =  P[2]*dx + P[3]*dy;
    float yr = -P[3]*dx + P[2]*dy;
    float e = __expf(-(xr*xr*P[4] + yr*yr*P[5]));
    mix += e * (P[6]/wsum);
  }
  float attn = 1.f/(1.f + __expf(-(4.f*mix - 2.f)));
  out[((size_t)(b*2))*NHW + p] = attn;
}

extern "C" void kernel_launch(void* const* d_in, const int* in_sizes, int n_in,
                              void* d_out, int out_size, void* d_ws, size_t ws_size,
                              hipStream_t stream){
  const float* x        = (const float*)d_in[0];
  const float* hm_dw    = (const float*)d_in[1];
  const float* hm_pw1   = (const float*)d_in[2];
  const float* hm_g1    = (const float*)d_in[3];
  const float* hm_b1    = (const float*)d_in[4];
  const float* hm_c3    = (const float*)d_in[5];
  const float* hm_g2    = (const float*)d_in[6];
  const float* hm_b2    = (const float*)d_in[7];
  const float* hm_out_w = (const float*)d_in[8];
  const float* hm_out_b = (const float*)d_in[9];
  const float* r_dw     = (const float*)d_in[10];
  const float* r_pw1    = (const float*)d_in[11];
  const float* r_g      = (const float*)d_in[12];
  const float* r_b      = (const float*)d_in[13];
  const float* r_out_w  = (const float*)d_in[14];
  const float* r_out_b  = (const float*)d_in[15];
  const float* log_alpha= (const float*)d_in[16];
  const float* mlp_w1   = (const float*)d_in[17];
  const float* mlp_b1   = (const float*)d_in[18];
  const float* mlp_w2   = (const float*)d_in[19];
  const float* mlp_b2   = (const float*)d_in[20];
  float* out = (float*)d_out;

  // workspace layout (~35 MiB):
  //   0        : h1     (B,128,NHW) bf16 = 33554432
  //   33554432 : heatF  (B,NHW) f32      = 524288
  //   34078720 : rmapF  (B,NHW) f32      = 524288
  //   34603008 : wT     (9,128,128) bf16 = 294912
  //   34897920 : wPW1h  (128,256) bf16   = 65536
  //   34963456 : wPW1r  (64,256) bf16    = 32768
  //   34996224 : centers (B,5,4) f32     = 640
  //   34996864 : params  (B,5,8) f32     = 1280
  char* ws = (char*)d_ws;
  bf16*  h1      = (bf16*)ws;
  float* heatF   = (float*)(ws + 33554432);
  float* rmapF   = (float*)(ws + 34078720);
  bf16*  wT      = (bf16*)(ws + 34603008);
  bf16*  wPW1h   = (bf16*)(ws + 34897920);
  bf16*  wPW1r   = (bf16*)(ws + 34963456);
  float* centers = (float*)(ws + 34996224);
  float* params  = (float*)(ws + 34996864);

  // weight conversions (tiny)
  k_cvt  <<<dim3(128), dim3(256), 0, stream>>>(hm_pw1, wPW1h, 128*256);
  k_cvt  <<<dim3(64),  dim3(256), 0, stream>>>(r_pw1,  wPW1r, 64*256);
  k_trans<<<dim3(576), dim3(256), 0, stream>>>(hm_c3, wT);

  // heat branch: fused dw+pw1+bn/relu -> h1 (bf16)
  k_pw_fused<8,0><<<dim3(2048), dim3(256), 0, stream>>>(x, hm_dw, wPW1h, hm_g1, hm_b1,
                                                        (const float*)nullptr, (const float*)nullptr,
                                                        h1, (float*)nullptr);
  // radius branch: fused dw+pw+bn/relu+head -> rmapF
  k_pw_fused<4,1><<<dim3(2048), dim3(256), 0, stream>>>(x, r_dw, wPW1r, r_g, r_b,
                                                        r_out_w, r_out_b,
                                                        (bf16*)nullptr, rmapF);
  // c3 + bn/relu + heat head -> heatF + out ch1
  k_c3<<<dim3(2048), dim3(256), 0, stream>>>(h1, wT, hm_g2, hm_b2, hm_out_w, hm_out_b, heatF, out);
  // peaks/topk -> centers; sample+MLP -> params; mixture -> attn (out ch0)
  k_topk<<<dim3(NB), dim3(256), 0, stream>>>(heatF, centers);
  k_params<<<dim3(NB), dim3(256), 0, stream>>>(x, rmapF, centers, mlp_w1, mlp_b1, mlp_w2, mlp_b2, log_alpha, params);
  k_attn<<<dim3(64, NB), dim3(256), 0, stream>>>(params, out);
}

// Round 4
// 780.414 us; speedup vs baseline: 1.8306x; 1.8306x over previous
//
#include <hip/hip_runtime.h>
#include <hip/hip_bf16.h>
#include <math.h>

typedef __hip_bfloat16 bf16;
using short8 = __attribute__((ext_vector_type(8))) short;
using f32x4  = __attribute__((ext_vector_type(4))) float;

#define NB 8
#define NC 256
#define NH 128
#define NW 128
#define NHW 16384
#define MID 128

__device__ __forceinline__ float b2f(bf16 v){ return __bfloat162float(v); }
__device__ __forceinline__ bf16 f2b(float v){ return __float2bfloat16(v); }
#define BN_S 0.9999950000374997f  /* 1/sqrt(1+1e-5) */

// ---------------- f32 -> bf16 weight convert ----------------
__global__ __launch_bounds__(256) void k_cvt(const float* __restrict__ src, bf16* __restrict__ dst, int n){
  int i = blockIdx.x*256 + threadIdx.x;
  if(i < n) dst[i] = f2b(src[i]);
}

// ---------------- hm_c3 (m,c,3,3) f32 -> (tau,m,c) bf16 ----------------
__global__ __launch_bounds__(256) void k_trans(const float* __restrict__ src, bf16* __restrict__ dst){
  int i = blockIdx.x*256 + threadIdx.x;
  if(i >= MID*MID*9) return;
  int tau = i % 9; int c = (i/9) % MID; int m = i/(9*MID);
  dst[((size_t)tau*MID + m)*MID + c] = f2b(src[i]);
}

// ============ depthwise 3x3 pad=1: f32 in -> bf16 out, LDS row staging ============
// grid (16, C, B); block handles 8 rows x 128 cols of one (b,c) plane
__global__ __launch_bounds__(256) void k_dw(const float* __restrict__ x,
                                            const float* __restrict__ w9,
                                            bf16* __restrict__ out){
  __shared__ float tile[10][132];   // rows y0-1..y0+8, cols 0..127 (132 pad: stride 528B, 16B-mult)
  int tid = threadIdx.x;
  int c = blockIdx.y, b = blockIdx.z;
  int y0 = blockIdx.x*8;
  const float* xp = x + ((size_t)(b*NC + c))*NHW;
  // stage 10 rows x 128 f32 = 320 float4
  for(int g = tid; g < 320; g += 256){
    int row = g >> 5, col4 = g & 31;
    int gy = y0 - 1 + row;
    float4 v = make_float4(0.f,0.f,0.f,0.f);
    if(gy >= 0 && gy < NH) v = *(const float4*)(xp + gy*NW + col4*4);
    *(float4*)&tile[row][col4*4] = v;
  }
  float wf[9];
  #pragma unroll
  for(int i=0;i<9;i++) wf[i] = w9[c*9+i];
  __syncthreads();
  int r  = tid >> 5;        // 0..7
  int c0 = (tid & 31)*4;    // 0..124
  float tap[3][6];
  #pragma unroll
  for(int dr=0;dr<3;dr++){
    #pragma unroll
    for(int cc=0;cc<6;cc++){
      int col = c0 - 1 + cc;
      float tv = tile[r+dr][(col<0)?0:((col>127)?127:col)];
      tap[dr][cc] = (col>=0 && col<NW) ? tv : 0.f;
    }
  }
  ushort4 ov;
  ushort* ovp = (ushort*)&ov;
  #pragma unroll
  for(int i=0;i<4;i++){
    float a = 0.f;
    #pragma unroll
    for(int dr=0;dr<3;dr++){
      #pragma unroll
      for(int dc=0;dc<3;dc++) a += tap[dr][i+dc]*wf[dr*3+dc];
    }
    bf16 ab = f2b(a);
    ovp[i] = *(ushort*)&ab;
  }
  *(ushort4*)(out + ((size_t)(b*NC+c))*NHW + (y0+r)*NW + c0) = ov;
}

// ============ pure pointwise GEMM (bf16 in, K=256) + bn/relu + epilogue ============
// MODE 0: store all M channels bf16 (h1); MODE 1: radius head -> rmapF
// Full-K B-tile staged up-front (one barrier), then barrier-free MFMA loop.
template<int MT, int MODE>
__global__ __launch_bounds__(256) void k_pw(const bf16* __restrict__ in,    // (B,256,NHW) bf16
                                            const bf16* __restrict__ wA,    // (M,256) bf16
                                            const float* __restrict__ g,
                                            const float* __restrict__ bias,
                                            const float* __restrict__ hw,
                                            const float* __restrict__ hb,
                                            bf16*  __restrict__ outCh,
                                            float* __restrict__ outMap){
  __shared__ ushort ldsB[64][264];  // [pixel][k] pad 256->264 (row 528B: 16B-mult, 2-way banks)
  const int M = MT*16;
  int tid = threadIdx.x;
  int bidx = blockIdx.x;
  int b = bidx >> 8;
  int p0 = (bidx & 255)*64;
  int lane = tid & 63, wave = tid >> 6;
  const ushort* inU = (const ushort*)(in + (size_t)b*NC*NHW);
  const ushort* wU  = (const ushort*)wA;

  // stage: each thread gathers 64 channels' values for its pixel (8 groups of ushort8)
  #pragma unroll
  for(int gg=0;gg<8;gg++){
    int ch0 = wave*64 + gg*8;
    union { ushort u[8]; short8 v; } t;
    #pragma unroll
    for(int j=0;j<8;j++) t.u[j] = inU[(size_t)(ch0+j)*NHW + p0 + lane];
    *(short8*)&ldsB[lane][ch0] = t.v;
  }
  __syncthreads();

  f32x4 acc[MT];
  #pragma unroll
  for(int i=0;i<MT;i++){
    #pragma unroll
    for(int r=0;r<4;r++) acc[i][r] = 0.f;
  }
  int n = lane & 15, quad = lane >> 4;
  #pragma unroll
  for(int k0=0;k0<NC;k0+=32){
    short8 bfrag = *(const short8*)&ldsB[wave*16 + n][k0 + quad*8];
    #pragma unroll
    for(int mt=0;mt<MT;mt++){
      short8 afrag = *(const short8*)&wU[(size_t)(mt*16 + n)*NC + k0 + quad*8];
      acc[mt] = __builtin_amdgcn_mfma_f32_16x16x32_bf16(afrag, bfrag, acc[mt], 0, 0, 0);
    }
  }

  int pix = p0 + wave*16 + n;
  if(MODE == 0){
    #pragma unroll
    for(int mt=0;mt<MT;mt++){
      #pragma unroll
      for(int r=0;r<4;r++){
        int m = mt*16 + quad*4 + r;
        float v = acc[mt][r]*(g[m]*BN_S) + bias[m];
        outCh[((size_t)(b*M + m))*NHW + pix] = f2b(fmaxf(v, 0.f));
      }
    }
  }else{
    float ph = 0.f;
    #pragma unroll
    for(int mt=0;mt<MT;mt++){
      #pragma unroll
      for(int r=0;r<4;r++){
        int m = mt*16 + quad*4 + r;
        float v = acc[mt][r]*(g[m]*BN_S) + bias[m];
        ph += fmaxf(v, 0.f) * hw[m];
      }
    }
    ph += __shfl_xor(ph, 16);
    ph += __shfl_xor(ph, 32);
    if(lane < 16){
      float sg = 1.f/(1.f + expf(-(ph + hb[0])));
      outMap[(size_t)b*NHW + pix] = 0.03f + sg*0.37f;
    }
  }
}

// ============ 3x3 conv MID->MID + bn/relu + heat head + sigmoid ============
// per-dy: stage row (all 128 ch, 66 cols w/ halo) in [col][ch] layout, then pure LDS+MFMA
__global__ __launch_bounds__(256) void k_c3(const bf16* __restrict__ in,   // h1 (B,128,NHW)
                                            const bf16* __restrict__ wT,   // (tau,m,c)
                                            const float* __restrict__ g,
                                            const float* __restrict__ bias,
                                            const float* __restrict__ hw,
                                            const float* __restrict__ hb,
                                            float* __restrict__ heatF,
                                            float* __restrict__ out){
  __shared__ ushort ldsH[66][136];  // [col 0..65 = x0-1..x0+64][ch pad 128->136 (272B rows)]
  int tid = threadIdx.x;
  int bidx = blockIdx.x;
  int b = bidx >> 8;
  int p0 = (bidx & 255)*64;
  int y  = p0 >> 7;
  int x0 = p0 & 127;
  const ushort* inU = (const ushort*)(in + (size_t)b*MID*NHW);
  const ushort* wU  = (const ushort*)wT;
  int lane = tid & 63, wave = tid >> 6;
  int n = lane & 15, quad = lane >> 4;
  f32x4 acc[8];
  #pragma unroll
  for(int i=0;i<8;i++){
    #pragma unroll
    for(int r=0;r<4;r++) acc[i][r] = 0.f;
  }
  for(int dy=0;dy<3;dy++){
    int yy = y + dy - 1;
    bool rowok = (yy>=0) && (yy<NH);
    __syncthreads();
    // stage: 66 cols x 16 ch-groups = 1056 ushort8
    for(int gg = tid; gg < 1056; gg += 256){
      int col = gg % 66, chg = gg / 66;
      int gcol = x0 - 1 + col;
      bool ok = rowok && (gcol>=0) && (gcol<NW);
      union { ushort u[8]; short8 v; } t;
      #pragma unroll
      for(int j=0;j<8;j++){
        t.u[j] = ok ? inU[(size_t)(chg*8+j)*NHW + yy*NW + gcol] : (ushort)0;
      }
      *(short8*)&ldsH[col][chg*8] = t.v;
    }
    __syncthreads();
    for(int dx=0;dx<3;dx++){
      int tau = dy*3 + dx;
      const ushort* wtb = wU + (size_t)tau*MID*MID;
      #pragma unroll
      for(int k0=0;k0<MID;k0+=32){
        short8 bfrag = *(const short8*)&ldsH[wave*16 + n + dx][k0 + quad*8];
        #pragma unroll
        for(int mt=0;mt<8;mt++){
          short8 afrag = *(const short8*)&wtb[(size_t)(mt*16 + n)*MID + k0 + quad*8];
          acc[mt] = __builtin_amdgcn_mfma_f32_16x16x32_bf16(afrag, bfrag, acc[mt], 0, 0, 0);
        }
      }
    }
  }
  float ph = 0.f;
  #pragma unroll
  for(int mt=0;mt<8;mt++){
    #pragma unroll
    for(int r=0;r<4;r++){
      int m = mt*16 + quad*4 + r;
      float v = acc[mt][r]*(g[m]*BN_S) + bias[m];
      ph += fmaxf(v, 0.f) * hw[m];
    }
  }
  ph += __shfl_xor(ph, 16);
  ph += __shfl_xor(ph, 32);
  if(lane < 16){
    int pix = p0 + wave*16 + lane;
    float sg = 1.f/(1.f + expf(-(ph + hb[0])));
    heatF[(size_t)b*NHW + pix] = sg;
    out[((size_t)(b*2+1))*NHW + pix] = sg;
  }
}

// ---------------- topk stage 1: per-512px-block top-5 ----------------
__global__ __launch_bounds__(256) void k_topk1(const float* __restrict__ heat,
                                               float* __restrict__ sv_g,   // (B,32,5)
                                               int*   __restrict__ si_g){
  __shared__ float sv[256*5];
  __shared__ int   si[256*5];
  int blk = blockIdx.x, b = blockIdx.y, tid = threadIdx.x;
  const float* hb = heat + (size_t)b*NHW;
  float tv[5]; int ti[5];
  #pragma unroll
  for(int i=0;i<5;i++){ tv[i] = -1.f; ti[i] = 0x7fffffff; }
  for(int s=0;s<2;s++){
    int p = blk*512 + s*256 + tid;
    int y = p >> 7, x = p & 127;
    float v = hb[p];
    float mx = v;
    for(int dy=-1;dy<=1;dy++){
      int yy = y+dy; if(yy<0||yy>=NH) continue;
      for(int dx=-1;dx<=1;dx++){
        int xc = x+dx; if(xc<0||xc>=NW) continue;
        mx = fmaxf(mx, hb[yy*NW+xc]);
      }
    }
    float pv = (v == mx) ? v : 0.f;
    #pragma unroll
    for(int j=0;j<5;j++){
      if(pv > tv[j] || (pv == tv[j] && p < ti[j])){
        for(int q=4;q>j;q--){ tv[q]=tv[q-1]; ti[q]=ti[q-1]; }
        tv[j] = pv; ti[j] = p;
        break;
      }
    }
  }
  #pragma unroll
  for(int i=0;i<5;i++){ sv[tid*5+i] = tv[i]; si[tid*5+i] = ti[i]; }
  __syncthreads();
  if(tid < 64){
    float mv[5]; int mi[5];
    #pragma unroll
    for(int i=0;i<5;i++){ mv[i] = -1.f; mi[i] = 0x7fffffff; }
    for(int s=0;s<4;s++){
      int t2 = tid + s*64;
      for(int i=0;i<5;i++){
        float pv = sv[t2*5+i]; int pi = si[t2*5+i];
        for(int j=0;j<5;j++){
          if(pv > mv[j] || (pv == mv[j] && pi < mi[j])){
            for(int q=4;q>j;q--){ mv[q]=mv[q-1]; mi[q]=mi[q-1]; }
            mv[j] = pv; mi[j] = pi;
            break;
          }
        }
      }
    }
    for(int i=0;i<5;i++){ sv[tid*5+i] = mv[i]; si[tid*5+i] = mi[i]; }
  }
  __syncthreads();
  if(tid == 0){
    float fv[5]; int fi[5];
    #pragma unroll
    for(int i=0;i<5;i++){ fv[i] = -1.f; fi[i] = 0x7fffffff; }
    for(int t2=0;t2<64;t2++){
      for(int i=0;i<5;i++){
        float pv = sv[t2*5+i]; int pi = si[t2*5+i];
        for(int j=0;j<5;j++){
          if(pv > fv[j] || (pv == fv[j] && pi < fi[j])){
            for(int q=4;q>j;q--){ fv[q]=fv[q-1]; fi[q]=fi[q-1]; }
            fv[j] = pv; fi[j] = pi;
            break;
          }
        }
      }
    }
    for(int i=0;i<5;i++){
      sv_g[(b*32 + blk)*5 + i] = fv[i];
      si_g[(b*32 + blk)*5 + i] = fi[i];
    }
  }
}

// ---------------- topk stage 2: rank-select over 160 candidates -> centers ----------------
__global__ __launch_bounds__(256) void k_topk2(const float* __restrict__ sv_g,
                                               const int*   __restrict__ si_g,
                                               float* __restrict__ centers){
  __shared__ float cv[160];
  __shared__ int   ci[160];
  int b = blockIdx.x, tid = threadIdx.x;
  if(tid < 160){ cv[tid] = sv_g[b*160 + tid]; ci[tid] = si_g[b*160 + tid]; }
  __syncthreads();
  if(tid < 160){
    float v = cv[tid]; int idx = ci[tid];
    int rank = 0;
    for(int j=0;j<160;j++){
      float vj = cv[j]; int ij = ci[j];
      rank += (vj > v || (vj == v && ij < idx)) ? 1 : 0;
    }
    if(rank < 5){
      float valid = (v >= 0.1f) ? 1.f : 0.f;
      float row = (float)(idx >> 7);
      float col = (float)(idx & 127);
      float ny = 2.f*row/127.f - 1.f;
      float nx = 2.f*col/127.f - 1.f;
      float* cp = centers + (b*5+rank)*4;
      cp[0] = nx*valid; cp[1] = ny*valid; cp[2] = v; cp[3] = valid;
    }
  }
}

// ---------------- bilinear sample + MLP -> per-(b,k) gaussian params (f32 exact) ----------------
__global__ __launch_bounds__(256) void k_params(const float* __restrict__ x,
                                                const float* __restrict__ rmap,
                                                const float* __restrict__ centers,
                                                const float* __restrict__ w1,
                                                const float* __restrict__ b1,
                                                const float* __restrict__ w2,
                                                const float* __restrict__ b2,
                                                const float* __restrict__ log_alpha,
                                                float* __restrict__ params){
  __shared__ float feat[NC];
  __shared__ float hmid[128];
  __shared__ float pp[4];
  int b = blockIdx.x, tid = threadIdx.x;
  for(int k=0;k<5;k++){
    float cx = centers[(b*5+k)*4+0];
    float cy = centers[(b*5+k)*4+1];
    float valid = centers[(b*5+k)*4+3];
    float px = fminf(fmaxf((cx+1.f)*0.5f*(NW-1), 0.f), (float)(NW-1));
    float py = fminf(fmaxf((cy+1.f)*0.5f*(NH-1), 0.f), (float)(NH-1));
    int x0 = (int)floorf(px); int x1 = min(x0+1, NW-1);
    int y0 = (int)floorf(py); int y1 = min(y0+1, NH-1);
    float wx = px - (float)x0, wy = py - (float)y0;
    {
      const float* xb = x + ((size_t)b*NC + tid)*NHW;
      float v00 = xb[y0*NW+x0], v01 = xb[y0*NW+x1];
      float v10 = xb[y1*NW+x0], v11 = xb[y1*NW+x1];
      feat[tid] = (1.f-wy)*((1.f-wx)*v00 + wx*v01) + wy*((1.f-wx)*v10 + wx*v11);
    }
    __syncthreads();
    if(tid < 128){
      float a = b1[tid];
      for(int c=0;c<NC;c++) a += feat[c]*w1[c*128+tid];
      hmid[tid] = fmaxf(a, 0.f);
    }
    __syncthreads();
    if(tid < 4){
      float a = b2[tid];
      for(int j=0;j<128;j++) a += hmid[j]*w2[j*4+tid];
      pp[tid] = a;
    }
    __syncthreads();
    if(tid == 0){
      const float* rb = rmap + (size_t)b*NHW;
      float r00 = rb[y0*NW+x0], r01 = rb[y0*NW+x1];
      float r10 = rb[y1*NW+x0], r11 = rb[y1*NW+x1];
      float rk = (1.f-wy)*((1.f-wx)*r00 + wx*r01) + wy*((1.f-wx)*r10 + wx*r11);
      float la = log_alpha[0];
      float alpha = logf(1.f + expf(la));
      float dsx = tanhf(pp[0])*0.08f;
      float dsy = tanhf(pp[1])*0.08f;
      float theta = tanhf(pp[2])*3.14159265358979323846f;
      float wgt = 1.f/(1.f + expf(-pp[3]));
      float sx = fminf(fmaxf(alpha*rk + dsx, 0.05f), 0.45f);
      float sy = fminf(fmaxf(alpha*rk*1.5f + dsy, 0.05f), 0.45f);
      float* P = params + (b*5+k)*8;
      P[0] = cx; P[1] = cy;
      P[2] = cosf(theta); P[3] = sinf(theta);
      P[4] = 1.f/(2.f*sx*sx + 1e-6f);
      P[5] = 1.f/(2.f*sy*sy + 1e-6f);
      P[6] = wgt*valid; P[7] = valid;
    }
    __syncthreads();
  }
}

// ---------------- gaussian mixture -> attn (out ch0) ----------------
__global__ __launch_bounds__(256) void k_attn(const float* __restrict__ params,
                                              float* __restrict__ out){
  int tid = threadIdx.x;
  int p = blockIdx.x*256 + tid;
  int b = blockIdx.y;
  int y = p >> 7, x = p & 127;
  float gx = -1.f + 2.f*(float)x/127.f;
  float gy = -1.f + 2.f*(float)y/127.f;
  const float* Pb = params + b*40;
  float wsum = 0.f;
  #pragma unroll
  for(int k=0;k<5;k++) wsum += Pb[k*8+6];
  wsum = fmaxf(wsum, 1e-6f);
  float mix = 0.f;
  #pragma unroll
  for(int k=0;k<5;k++){
    const float* P = Pb + k*8;
    float dx = gx - P[0], dy = gy - P[1];
    float xr =  P[2]*dx + P[3]*dy;
    float yr = -P[3]*dx + P[2]*dy;
    float e = __expf(-(xr*xr*P[4] + yr*yr*P[5]));
    mix += e * (P[6]/wsum);
  }
  float attn = 1.f/(1.f + __expf(-(4.f*mix - 2.f)));
  out[((size_t)(b*2))*NHW + p] = attn;
}

extern "C" void kernel_launch(void* const* d_in, const int* in_sizes, int n_in,
                              void* d_out, int out_size, void* d_ws, size_t ws_size,
                              hipStream_t stream){
  const float* x        = (const float*)d_in[0];
  const float* hm_dw    = (const float*)d_in[1];
  const float* hm_pw1   = (const float*)d_in[2];
  const float* hm_g1    = (const float*)d_in[3];
  const float* hm_b1    = (const float*)d_in[4];
  const float* hm_c3    = (const float*)d_in[5];
  const float* hm_g2    = (const float*)d_in[6];
  const float* hm_b2    = (const float*)d_in[7];
  const float* hm_out_w = (const float*)d_in[8];
  const float* hm_out_b = (const float*)d_in[9];
  const float* r_dw     = (const float*)d_in[10];
  const float* r_pw1    = (const float*)d_in[11];
  const float* r_g      = (const float*)d_in[12];
  const float* r_b      = (const float*)d_in[13];
  const float* r_out_w  = (const float*)d_in[14];
  const float* r_out_b  = (const float*)d_in[15];
  const float* log_alpha= (const float*)d_in[16];
  const float* mlp_w1   = (const float*)d_in[17];
  const float* mlp_b1   = (const float*)d_in[18];
  const float* mlp_w2   = (const float*)d_in[19];
  const float* mlp_b2   = (const float*)d_in[20];
  float* out = (float*)d_out;

  // workspace (~102.2 MB), sequential reuse of dwX for both branches:
  //   0         : dwX   (B,256,NHW) bf16 = 67108864
  //   67108864  : h1    (B,128,NHW) bf16 = 33554432
  //   100663296 : heatF (B,NHW) f32      = 524288
  //   101187584 : rmapF (B,NHW) f32      = 524288
  //   101711872 : wT    (9,128,128) bf16 = 294912
  //   102006784 : wPW1h (128,256) bf16   = 65536
  //   102072320 : wPW1r (64,256) bf16    = 32768
  //   102105088 : topk sv (8*32*5) f32   = 5120
  //   102110208 : topk si (8*32*5) i32   = 5120
  //   102115328 : centers (B,5,4) f32    = 640
  //   102115968 : params  (B,5,8) f32    = 1280
  char* ws = (char*)d_ws;
  bf16*  dwX     = (bf16*)ws;
  bf16*  h1      = (bf16*)(ws + 67108864);
  float* heatF   = (float*)(ws + 100663296);
  float* rmapF   = (float*)(ws + 101187584);
  bf16*  wT      = (bf16*)(ws + 101711872);
  bf16*  wPW1h   = (bf16*)(ws + 102006784);
  bf16*  wPW1r   = (bf16*)(ws + 102072320);
  float* tsv     = (float*)(ws + 102105088);
  int*   tsi     = (int*)  (ws + 102110208);
  float* centers = (float*)(ws + 102115328);
  float* params  = (float*)(ws + 102115968);

  // weight prep (tiny)
  k_cvt  <<<dim3(128), dim3(256), 0, stream>>>(hm_pw1, wPW1h, 128*256);
  k_cvt  <<<dim3(64),  dim3(256), 0, stream>>>(r_pw1,  wPW1r, 64*256);
  k_trans<<<dim3(576), dim3(256), 0, stream>>>(hm_c3, wT);

  // heat branch
  k_dw<<<dim3(16, NC, NB), dim3(256), 0, stream>>>(x, hm_dw, dwX);
  k_pw<8,0><<<dim3(2048), dim3(256), 0, stream>>>(dwX, wPW1h, hm_g1, hm_b1,
                                                  (const float*)nullptr, (const float*)nullptr,
                                                  h1, (float*)nullptr);
  // radius branch (reuses dwX)
  k_dw<<<dim3(16, NC, NB), dim3(256), 0, stream>>>(x, r_dw, dwX);
  k_pw<4,1><<<dim3(2048), dim3(256), 0, stream>>>(dwX, wPW1r, r_g, r_b,
                                                  r_out_w, r_out_b,
                                                  (bf16*)nullptr, rmapF);
  // c3 + heat head
  k_c3<<<dim3(2048), dim3(256), 0, stream>>>(h1, wT, hm_g2, hm_b2, hm_out_w, hm_out_b, heatF, out);
  // topk (2-stage) -> centers; params; attn
  k_topk1<<<dim3(32, NB), dim3(256), 0, stream>>>(heatF, tsv, tsi);
  k_topk2<<<dim3(NB), dim3(256), 0, stream>>>(tsv, tsi, centers);
  k_params<<<dim3(NB), dim3(256), 0, stream>>>(x, rmapF, centers, mlp_w1, mlp_b1, mlp_w2, mlp_b2, log_alpha, params);
  k_attn<<<dim3(64, NB), dim3(256), 0, stream>>>(params, out);
}